// Round 1
// baseline (322.406 us; speedup 1.0000x reference)
//
#include <hip/hip_runtime.h>
#include <hip/hip_bf16.h>

#define HEADS 12
#define HD 64
#define DMODEL 768
#define TSEQ 2048
#define BATCH 2
#define NTOK (BATCH*TSEQ)   // 4096
#define NQKV (3*DMODEL)     // 2304

typedef __attribute__((ext_vector_type(8))) short bf16x8;
typedef __attribute__((ext_vector_type(4))) float f32x4;

static __device__ inline float bf2f(short s) {
  union { float f; unsigned u; } cv; cv.u = ((unsigned)(unsigned short)s) << 16; return cv.f;
}
static __device__ inline short f2bf(float f) {
  union { float f; unsigned u; } cv; cv.f = f;
  unsigned u = cv.u;
  unsigned r = u + 0x7FFF + ((u >> 16) & 1);   // RNE
  return (short)(r >> 16);
}

// ---------------- conversion / packing ----------------
__global__ void cvt_kernel(const float* __restrict__ x,
                           const float* __restrict__ Wq, const float* __restrict__ Wk,
                           const float* __restrict__ Wv,
                           const float* __restrict__ bq, const float* __restrict__ bk,
                           const float* __restrict__ bv,
                           short* __restrict__ Xb, short* __restrict__ Wc,
                           float* __restrict__ bc) {
  const int NX = NTOK*DMODEL;             // 3145728
  const int WSZ = DMODEL*DMODEL;          // 589824
  const int NW = 3*WSZ;                   // 1769472
  const int total = NX + NW + NQKV;
  for (int i = blockIdx.x*blockDim.x + threadIdx.x; i < total; i += gridDim.x*blockDim.x) {
    if (i < NX) {
      Xb[i] = f2bf(x[i]);
    } else if (i < NX + NW) {
      int j = i - NX;
      float v = (j < WSZ) ? Wq[j] : (j < 2*WSZ) ? Wk[j - WSZ] : Wv[j - 2*WSZ];
      Wc[j] = f2bf(v);
    } else {
      int o = i - NX - NW;
      bc[o] = (o < DMODEL) ? bq[o] : (o < 2*DMODEL) ? bk[o - DMODEL] : bv[o - 2*DMODEL];
    }
  }
}

// ---------------- fused QKV GEMM:  C[t][o] = Xb[t,:] . Wc[o,:] + bc[o] ----------------
__global__ __launch_bounds__(256) void qkv_gemm(const short* __restrict__ Xb,
                                                const short* __restrict__ Wc,
                                                const float* __restrict__ bc,
                                                short* __restrict__ Q, short* __restrict__ K,
                                                short* __restrict__ V, short* __restrict__ Vt) {
  const int nbn = NQKV/128;           // 18
  int bm = blockIdx.x / nbn, bn = blockIdx.x % nbn;
  int trow = bm*128, tcol = bn*128;
  int tid = threadIdx.x;
  int w = tid >> 6, l = tid & 63;
  int wr = w >> 1, wc = w & 1;
  int lr = l & 15, lg = l >> 4;

  f32x4 acc[4][4];
  for (int m=0;m<4;m++) for (int n=0;n<4;n++) acc[m][n] = (f32x4)0.f;

  for (int kc = 0; kc < DMODEL/32; kc++) {
    int k0 = kc*32 + lg*8;
    bf16x8 a[4], bb[4];
    for (int m=0;m<4;m++)
      a[m] = *(const bf16x8*)&Xb[(size_t)(trow + wr*64 + m*16 + lr)*DMODEL + k0];
    for (int n=0;n<4;n++)
      bb[n] = *(const bf16x8*)&Wc[(size_t)(tcol + wc*64 + n*16 + lr)*DMODEL + k0];
    for (int m=0;m<4;m++)
      for (int n=0;n<4;n++)
        acc[m][n] = __builtin_amdgcn_mfma_f32_16x16x32_bf16(a[m], bb[n], acc[m][n], 0, 0, 0);
  }

  for (int m=0;m<4;m++) for (int n=0;n<4;n++) {
    int o = tcol + wc*64 + n*16 + lr;
    float bias = bc[o];
    int sel = o / DMODEL;
    int h = (o - sel*DMODEL) >> 6;
    int d = o & 63;
    for (int j=0;j<4;j++) {
      int t = trow + wr*64 + m*16 + lg*4 + j;
      short bv16 = f2bf(acc[m][n][j] + bias);
      int b = t >> 11, tt = t & (TSEQ-1);
      int bh = b*HEADS + h;
      size_t idx = ((size_t)bh*TSEQ + tt)*HD + d;
      if (sel == 0) Q[idx] = bv16;
      else if (sel == 1) K[idx] = bv16;
      else {
        V[idx] = bv16;
        Vt[((size_t)bh*HD + d)*TSEQ + tt] = bv16;
      }
    }
  }
}

// ---------------- per-(b,h,d) column sum of V ----------------
__global__ void vsum_kernel(const short* __restrict__ V, float* __restrict__ vs) {
  int bh = blockIdx.x; int d = threadIdx.x;  // 64 threads
  const short* p = V + (size_t)bh*TSEQ*HD + d;
  float s = 0.f;
  for (int t = 0; t < TSEQ; t++) s += bf2f(p[(size_t)t*HD]);
  vs[bh*HD + d] = s;
}

// ---------------- flash attention + shaped epilogue ----------------
__global__ __launch_bounds__(256) void attn_kernel(
    const short* __restrict__ Q, const short* __restrict__ K,
    const short* __restrict__ V, const short* __restrict__ Vt,
    const float* __restrict__ vs,
    const float* __restrict__ alpha, const float* __restrict__ beta,
    const float* __restrict__ gamma, const float* __restrict__ Cc,
    float* __restrict__ out) {
  const int nqt = TSEQ/64;            // 32
  int bh = blockIdx.x / nqt;
  int qt = blockIdx.x % nqt;
  int b = bh / HEADS, h = bh % HEADS;

  int tid = threadIdx.x;
  int w = tid >> 6, l = tid & 63;
  int lr = l & 15, lg = l >> 4;
  int qbase = qt*64 + w*16;

  __shared__ __align__(16) short plds[4][16][72];  // pad 64->72 keeps 16B align, breaks bank stride

  const short* Qp  = Q  + (size_t)bh*TSEQ*HD;
  const short* Kp  = K  + (size_t)bh*TSEQ*HD;
  const short* Vtp = Vt + (size_t)bh*HD*TSEQ;

  bf16x8 qa[2];
  qa[0] = *(const bf16x8*)&Qp[(size_t)(qbase + lr)*HD + lg*8];
  qa[1] = *(const bf16x8*)&Qp[(size_t)(qbase + lr)*HD + 32 + lg*8];

  float m[4], ll[4];
  f32x4 o[4];
  for (int j=0;j<4;j++) { m[j] = -1e30f; ll[j] = 0.f; }
  for (int f=0;f<4;f++) o[f] = (f32x4)0.f;

  const float scale = 0.125f;   // 1/sqrt(64)

  for (int kt = 0; kt < TSEQ/64; kt++) {
    int kbase = kt*64;
    f32x4 s[4];
    for (int f=0;f<4;f++) s[f] = (f32x4)0.f;
    for (int c=0;c<2;c++) {
      for (int f=0;f<4;f++) {
        bf16x8 kb = *(const bf16x8*)&Kp[(size_t)(kbase + f*16 + lr)*HD + c*32 + lg*8];
        s[f] = __builtin_amdgcn_mfma_f32_16x16x32_bf16(qa[c], kb, s[f], 0, 0, 0);
      }
    }
    // online softmax (rows = lg*4+j, cols = key within tile)
    float r[4];
    for (int j=0;j<4;j++) {
      float t0 = fmaxf(fmaxf(s[0][j], s[1][j]), fmaxf(s[2][j], s[3][j]));
      t0 = fmaxf(t0, __shfl_xor(t0, 1));
      t0 = fmaxf(t0, __shfl_xor(t0, 2));
      t0 = fmaxf(t0, __shfl_xor(t0, 4));
      t0 = fmaxf(t0, __shfl_xor(t0, 8));
      float mn = fmaxf(m[j], t0*scale);
      r[j] = __expf(m[j] - mn);
      m[j] = mn;
    }
    float psum[4] = {0.f, 0.f, 0.f, 0.f};
    for (int f=0;f<4;f++) {
      for (int j=0;j<4;j++) {
        float p = __expf(s[f][j]*scale - m[j]);
        psum[j] += p;
        plds[w][lg*4+j][f*16+lr] = f2bf(p);
      }
    }
    for (int j=0;j<4;j++) {
      float t = psum[j];
      t += __shfl_xor(t, 1);
      t += __shfl_xor(t, 2);
      t += __shfl_xor(t, 4);
      t += __shfl_xor(t, 8);
      ll[j] = ll[j]*r[j] + t;
    }
    for (int f=0;f<4;f++)
      for (int j=0;j<4;j++)
        o[f][j] *= r[j];
    __syncthreads();   // order LDS P writes vs reads (uniform loop count)
    for (int c=0;c<2;c++) {
      bf16x8 pa = *(const bf16x8*)&plds[w][lr][c*32 + lg*8];
      for (int f=0;f<4;f++) {
        bf16x8 vb = *(const bf16x8*)&Vtp[(size_t)(f*16 + lr)*TSEQ + kbase + c*32 + lg*8];
        o[f] = __builtin_amdgcn_mfma_f32_16x16x32_bf16(pa, vb, o[f], 0, 0, 0);
      }
    }
    __syncthreads();   // protect P buffer from next-iteration overwrite
  }

  float al = alpha[h], be = beta[h], ga = gamma[h], cc = Cc[h];
  const short* Vp = V + (size_t)bh*TSEQ*HD;
  const float* vsp = vs + bh*HD;
  for (int f=0;f<4;f++) {
    int d = f*16 + lr;
    float gv = ga*cc*vsp[d];
    for (int j=0;j<4;j++) {
      int qrow = qbase + lg*4 + j;
      float sv = o[f][j] / ll[j];
      float vv = bf2f(Vp[(size_t)qrow*HD + d]);
      out[((size_t)b*TSEQ + qrow)*DMODEL + h*HD + d] = al*vv + be*sv - gv;
    }
  }
}

extern "C" void kernel_launch(void* const* d_in, const int* in_sizes, int n_in,
                              void* d_out, int out_size, void* d_ws, size_t ws_size,
                              hipStream_t stream) {
  const float* x     = (const float*)d_in[0];
  const float* Wq    = (const float*)d_in[1];
  const float* bq    = (const float*)d_in[2];
  const float* Wk    = (const float*)d_in[3];
  const float* bk    = (const float*)d_in[4];
  const float* Wv    = (const float*)d_in[5];
  const float* bv    = (const float*)d_in[6];
  const float* alpha = (const float*)d_in[7];
  const float* beta  = (const float*)d_in[8];
  const float* gamma = (const float*)d_in[9];
  const float* Cc    = (const float*)d_in[10];
  float* out = (float*)d_out;

  char* ws = (char*)d_ws;
  size_t off = 0;
  auto alloc = [&](size_t bytes) -> void* {
    void* p = ws + off; off += (bytes + 255) & ~(size_t)255; return p;
  };
  short* Xb = (short*)alloc((size_t)NTOK*DMODEL*2);
  short* Wc = (short*)alloc((size_t)NQKV*DMODEL*2);
  float* bc = (float*)alloc((size_t)NQKV*4);
  short* Q  = (short*)alloc((size_t)BATCH*HEADS*TSEQ*HD*2);
  short* K  = (short*)alloc((size_t)BATCH*HEADS*TSEQ*HD*2);
  short* V  = (short*)alloc((size_t)BATCH*HEADS*TSEQ*HD*2);
  short* Vt = (short*)alloc((size_t)BATCH*HEADS*TSEQ*HD*2);
  float* vs = (float*)alloc((size_t)BATCH*HEADS*HD*4);

  cvt_kernel<<<2048, 256, 0, stream>>>(x, Wq, Wk, Wv, bq, bk, bv, Xb, Wc, bc);
  qkv_gemm<<<(NTOK/128)*(NQKV/128), 256, 0, stream>>>(Xb, Wc, bc, Q, K, V, Vt);
  vsum_kernel<<<BATCH*HEADS, 64, 0, stream>>>(V, vs);
  attn_kernel<<<BATCH*HEADS*(TSEQ/64), 256, 0, stream>>>(Q, K, V, Vt, vs, alpha, beta, gamma, Cc, out);
}

// Round 2
// 276.688 us; speedup vs baseline: 1.1652x; 1.1652x over previous
//
#include <hip/hip_runtime.h>
#include <hip/hip_bf16.h>

#define HEADS 12
#define HD 64
#define DMODEL 768
#define TSEQ 2048
#define BATCH 2
#define NTOK (BATCH*TSEQ)   // 4096
#define NQKV (3*DMODEL)     // 2304

typedef __attribute__((ext_vector_type(8))) short bf16x8;
typedef __attribute__((ext_vector_type(4))) short bf16x4;
typedef __attribute__((ext_vector_type(4))) float f32x4;

static __device__ inline float bf2f(short s) {
  union { float f; unsigned u; } cv; cv.u = ((unsigned)(unsigned short)s) << 16; return cv.f;
}
static __device__ inline short f2bf(float f) {
  union { float f; unsigned u; } cv; cv.f = f;
  unsigned u = cv.u;
  unsigned r = u + 0x7FFF + ((u >> 16) & 1);   // RNE
  return (short)(r >> 16);
}

// ---------------- conversion / packing ----------------
__global__ void cvt_kernel(const float* __restrict__ x,
                           const float* __restrict__ Wq, const float* __restrict__ Wk,
                           const float* __restrict__ Wv,
                           const float* __restrict__ bq, const float* __restrict__ bk,
                           const float* __restrict__ bv,
                           short* __restrict__ Xb, short* __restrict__ Wc,
                           float* __restrict__ bc) {
  const int NX = NTOK*DMODEL;             // 3145728
  const int WSZ = DMODEL*DMODEL;          // 589824
  const int NW = 3*WSZ;                   // 1769472
  const int total = NX + NW + NQKV;
  for (int i = blockIdx.x*blockDim.x + threadIdx.x; i < total; i += gridDim.x*blockDim.x) {
    if (i < NX) {
      Xb[i] = f2bf(x[i]);
    } else if (i < NX + NW) {
      int j = i - NX;
      float v = (j < WSZ) ? Wq[j] : (j < 2*WSZ) ? Wk[j - WSZ] : Wv[j - 2*WSZ];
      Wc[j] = f2bf(v);
    } else {
      int o = i - NX - NW;
      bc[o] = (o < DMODEL) ? bq[o] : (o < 2*DMODEL) ? bk[o - DMODEL] : bv[o - 2*DMODEL];
    }
  }
}

// ---------------- fused QKV GEMM:  C[t][o] = Xb[t,:] . Wc[o,:] + bc[o] ----------------
__global__ __launch_bounds__(256) void qkv_gemm(const short* __restrict__ Xb,
                                                const short* __restrict__ Wc,
                                                const float* __restrict__ bc,
                                                short* __restrict__ Q, short* __restrict__ K,
                                                short* __restrict__ V, short* __restrict__ Vt) {
  const int nbn = NQKV/128;           // 18
  int bm = blockIdx.x / nbn, bn = blockIdx.x % nbn;
  int trow = bm*128, tcol = bn*128;
  int tid = threadIdx.x;
  int w = tid >> 6, l = tid & 63;
  int wr = w >> 1, wc = w & 1;
  int lr = l & 15, lg = l >> 4;

  f32x4 acc[4][4];
  for (int m=0;m<4;m++) for (int n=0;n<4;n++) acc[m][n] = (f32x4)0.f;

  for (int kc = 0; kc < DMODEL/32; kc++) {
    int k0 = kc*32 + lg*8;
    bf16x8 a[4], bb[4];
    #pragma unroll
    for (int m=0;m<4;m++)
      a[m] = *(const bf16x8*)&Xb[(size_t)(trow + wr*64 + m*16 + lr)*DMODEL + k0];
    #pragma unroll
    for (int n=0;n<4;n++)
      bb[n] = *(const bf16x8*)&Wc[(size_t)(tcol + wc*64 + n*16 + lr)*DMODEL + k0];
    #pragma unroll
    for (int m=0;m<4;m++)
      #pragma unroll
      for (int n=0;n<4;n++)
        acc[m][n] = __builtin_amdgcn_mfma_f32_16x16x32_bf16(a[m], bb[n], acc[m][n], 0, 0, 0);
  }

  for (int m=0;m<4;m++) for (int n=0;n<4;n++) {
    int o = tcol + wc*64 + n*16 + lr;
    float bias = bc[o];
    int sel = o / DMODEL;
    int h = (o - sel*DMODEL) >> 6;
    int d = o & 63;
    for (int j=0;j<4;j++) {
      int t = trow + wr*64 + m*16 + lg*4 + j;
      short bv16 = f2bf(acc[m][n][j] + bias);
      int b = t >> 11, tt = t & (TSEQ-1);
      int bh = b*HEADS + h;
      size_t idx = ((size_t)bh*TSEQ + tt)*HD + d;
      if (sel == 0) Q[idx] = bv16;
      else if (sel == 1) K[idx] = bv16;
      else {
        V[idx] = bv16;
        Vt[((size_t)bh*HD + d)*TSEQ + tt] = bv16;
      }
    }
  }
}

// ---------------- per-(b,h,d) column sum of V — two-stage ----------------
__global__ __launch_bounds__(256) void vsum1(const short* __restrict__ V, float* __restrict__ part) {
  int bh = blockIdx.x >> 3, tc = blockIdx.x & 7;   // grid 24*8
  int d = threadIdx.x & 63, tg = threadIdx.x >> 6;
  const short* p = V + ((size_t)bh*TSEQ + tc*256)*HD + d;
  float s = 0.f;
  #pragma unroll 8
  for (int i = 0; i < 64; i++) s += bf2f(p[(size_t)(tg + i*4)*HD]);
  __shared__ float red[4][64];
  red[tg][d] = s;
  __syncthreads();
  if (tg == 0) part[(bh*8 + tc)*64 + d] = red[0][d] + red[1][d] + red[2][d] + red[3][d];
}
__global__ void vsum2(const float* __restrict__ part, float* __restrict__ vs) {
  int bh = blockIdx.x, d = threadIdx.x;  // 24 x 64
  float s = 0.f;
  for (int c = 0; c < 8; c++) s += part[(bh*8 + c)*64 + d];
  vs[bh*64 + d] = s;
}

// ---------------- flash attention (swapped QK^T, barrier-free) ----------------
__global__ __launch_bounds__(256) void attn_kernel(
    const short* __restrict__ Q, const short* __restrict__ K,
    const short* __restrict__ V, const short* __restrict__ Vt,
    const float* __restrict__ vs,
    const float* __restrict__ alpha, const float* __restrict__ beta,
    const float* __restrict__ gamma, const float* __restrict__ Cc,
    float* __restrict__ out) {
  const int nqt = TSEQ/64;            // 32
  int bh = blockIdx.x / nqt;
  int qt = blockIdx.x % nqt;
  int b = bh / HEADS, h = bh % HEADS;

  int tid = threadIdx.x;
  int w = tid >> 6, l = tid & 63;
  int lr = l & 15, lg = l >> 4;
  int qbase = qt*64 + w*16;

  // wave-private P strip: P[q=16][key=64] bf16, XOR-swizzled, no barriers needed
  __shared__ __align__(16) short plds[4][16*64];
  char* pl = (char*)&plds[w][0];
  const int swz = (lr & 7) << 4;

  const short* Qp  = Q  + (size_t)bh*TSEQ*HD;
  const short* Kp  = K  + (size_t)bh*TSEQ*HD;
  const short* Vtp = Vt + (size_t)bh*HD*TSEQ;

  bf16x8 qa[2];
  qa[0] = *(const bf16x8*)&Qp[(size_t)(qbase + lr)*HD + lg*8];
  qa[1] = *(const bf16x8*)&Qp[(size_t)(qbase + lr)*HD + 32 + lg*8];

  float m = -1e30f, ll = 0.f;
  f32x4 o[4];
  #pragma unroll
  for (int f=0;f<4;f++) o[f] = (f32x4)0.f;

  const float scale = 0.125f;   // 1/sqrt(64)

  for (int kt = 0; kt < TSEQ/64; kt++) {
    int kbase = kt*64;
    // S^T = K . Q^T : lane holds S[q = qbase+lr][key = kbase + f*16 + lg*4 + j]
    f32x4 s[4];
    #pragma unroll
    for (int f=0;f<4;f++) s[f] = (f32x4)0.f;
    #pragma unroll
    for (int c=0;c<2;c++) {
      #pragma unroll
      for (int f=0;f<4;f++) {
        bf16x8 kb = *(const bf16x8*)&Kp[(size_t)(kbase + f*16 + lr)*HD + c*32 + lg*8];
        s[f] = __builtin_amdgcn_mfma_f32_16x16x32_bf16(kb, qa[c], s[f], 0, 0, 0);
      }
    }
    // online softmax over keys for this lane's q (16 lane-local + 2 shfl)
    float tmax = s[0][0];
    #pragma unroll
    for (int f=0;f<4;f++)
      #pragma unroll
      for (int j=0;j<4;j++) tmax = fmaxf(tmax, s[f][j]);
    tmax = fmaxf(tmax, __shfl_xor(tmax, 16));
    tmax = fmaxf(tmax, __shfl_xor(tmax, 32));
    float mn = fmaxf(m, tmax*scale);
    float r = __expf(m - mn);
    m = mn;
    float p[4][4];
    float psum = 0.f;
    #pragma unroll
    for (int f=0;f<4;f++)
      #pragma unroll
      for (int j=0;j<4;j++) {
        p[f][j] = __expf(s[f][j]*scale - mn);
        psum += p[f][j];
      }
    psum += __shfl_xor(psum, 16);
    psum += __shfl_xor(psum, 32);
    ll = ll*r + psum;
    #pragma unroll
    for (int f=0;f<4;f++) o[f] *= r;
    // pack P (bf16 pairs) into swizzled LDS strip: row q=lr, bytes key*2
    #pragma unroll
    for (int f=0;f<4;f++) {
      int byteoff = (lr*128 + (f*16 + lg*4)*2) ^ swz;
      *(__hip_bfloat162*)(pl + byteoff)     = __float22bfloat162_rn(float2{p[f][0], p[f][1]});
      *(__hip_bfloat162*)(pl + byteoff + 4) = __float22bfloat162_rn(float2{p[f][2], p[f][3]});
    }
    // O^T += V^T . P^T  (A = Vt rows, B = P columns)
    #pragma unroll
    for (int c=0;c<2;c++) {
      bf16x8 pa = *(const bf16x8*)(pl + ((lr*128 + c*64 + lg*16) ^ swz));
      #pragma unroll
      for (int f=0;f<4;f++) {
        bf16x8 vb = *(const bf16x8*)&Vtp[(size_t)(f*16 + lr)*TSEQ + kbase + c*32 + lg*8];
        o[f] = __builtin_amdgcn_mfma_f32_16x16x32_bf16(vb, pa, o[f], 0, 0, 0);
      }
    }
  }

  // epilogue: out = alpha*V + beta*softmax(S)V - gamma*C*colsum(V)
  float al = alpha[h], be = beta[h], ga = gamma[h], cc = Cc[h];
  float inv = 1.f / ll;
  int qrow = qbase + lr;
  const short* Vp = V + (size_t)bh*TSEQ*HD;
  const float* vsp = vs + bh*HD;
  #pragma unroll
  for (int f=0;f<4;f++) {
    int d0 = f*16 + lg*4;
    bf16x4 vv4 = *(const bf16x4*)&Vp[(size_t)qrow*HD + d0];
    f32x4 vs4 = *(const f32x4*)&vsp[d0];
    f32x4 res;
    #pragma unroll
    for (int j=0;j<4;j++) {
      float sv = o[f][j] * inv;
      res[j] = al*bf2f(vv4[j]) + be*sv - ga*cc*vs4[j];
    }
    *(f32x4*)&out[((size_t)b*TSEQ + qrow)*DMODEL + h*HD + d0] = res;
  }
}

extern "C" void kernel_launch(void* const* d_in, const int* in_sizes, int n_in,
                              void* d_out, int out_size, void* d_ws, size_t ws_size,
                              hipStream_t stream) {
  const float* x     = (const float*)d_in[0];
  const float* Wq    = (const float*)d_in[1];
  const float* bq    = (const float*)d_in[2];
  const float* Wk    = (const float*)d_in[3];
  const float* bk    = (const float*)d_in[4];
  const float* Wv    = (const float*)d_in[5];
  const float* bv    = (const float*)d_in[6];
  const float* alpha = (const float*)d_in[7];
  const float* beta  = (const float*)d_in[8];
  const float* gamma = (const float*)d_in[9];
  const float* Cc    = (const float*)d_in[10];
  float* out = (float*)d_out;

  char* ws = (char*)d_ws;
  size_t off = 0;
  auto alloc = [&](size_t bytes) -> void* {
    void* p = ws + off; off += (bytes + 255) & ~(size_t)255; return p;
  };
  short* Xb = (short*)alloc((size_t)NTOK*DMODEL*2);
  short* Wc = (short*)alloc((size_t)NQKV*DMODEL*2);
  float* bc = (float*)alloc((size_t)NQKV*4);
  short* Q  = (short*)alloc((size_t)BATCH*HEADS*TSEQ*HD*2);
  short* K  = (short*)alloc((size_t)BATCH*HEADS*TSEQ*HD*2);
  short* V  = (short*)alloc((size_t)BATCH*HEADS*TSEQ*HD*2);
  short* Vt = (short*)alloc((size_t)BATCH*HEADS*TSEQ*HD*2);
  float* vs = (float*)alloc((size_t)BATCH*HEADS*HD*4);
  float* part = (float*)alloc((size_t)BATCH*HEADS*8*HD*4);

  cvt_kernel<<<2048, 256, 0, stream>>>(x, Wq, Wk, Wv, bq, bk, bv, Xb, Wc, bc);
  qkv_gemm<<<(NTOK/128)*(NQKV/128), 256, 0, stream>>>(Xb, Wc, bc, Q, K, V, Vt);
  vsum1<<<BATCH*HEADS*8, 256, 0, stream>>>(V, part);
  vsum2<<<BATCH*HEADS, 64, 0, stream>>>(part, vs);
  attn_kernel<<<BATCH*HEADS*(TSEQ/64), 256, 0, stream>>>(Q, K, V, Vt, vs, alpha, beta, gamma, Cc, out);
}